// Round 8
// baseline (671.677 us; speedup 1.0000x reference)
//
#include <hip/hip_runtime.h>
#include <math.h>

// out[b] = (1^T · Π_d C_d · P) · Π_d x[b,d] + bias — per-row scalars commute
// out of the batch-independent matrix chain. SINGLE fused kernel, low-LDS:
//   blocks 0..31   : fold 64-core chunks — cores staged in DOUBLE-BUFFERED
//                    batches of 8 (16 KB, prefetch under compute). Fan-in via
//                    flags; block 0 reduces the 32 partials in wave-0
//                    registers (two 16-matrix LDS passes reusing the same
//                    16 KB), projects -> pE, release-stores flags[0].
//   blocks 32..2079: one wave per row — do the compulsory 64 MB x-read FIRST
//                    (independent of pE), then THROTTLED acquire spin
//                    (s_sleep(64) between acquires: no L2 invalidate storm),
//                    epilogue out[b,o] = ldexp(p[o]*s_b, E) + bias[o].
// Round-7 lesson: LDS is per-kernel, not per-branch (98 KB -> 1 blk/CU), and
// tight agent-acquire spins thrash the XCD L2. Both fixed here: 18 KB LDS,
// __launch_bounds__(256,6) -> >=6 blk/CU, sleepy spins.
// Row products underflow fp32 to 0 exactly as the reference (absmax 0.0,
// verified rounds 1/5/6).

#define DFEAT 2048
#define R 16
#define NR2 256               // R*R
#define OUTD 64
#define CHUNK 64              // cores folded per chain block
#define BATCH 8               // cores staged per LDS batch
#define NBATCH (CHUNK / BATCH)    // 8 batches
#define NCHUNK (DFEAT / CHUNK)    // 32 chain blocks
#define MAGIC 0x7E57C0DE

__global__ __launch_bounds__(256, 6) void mps_fused(
        const float* __restrict__ cores, const float* __restrict__ proj,
        const float* __restrict__ x, const float* __restrict__ bias,
        float* __restrict__ out, float* __restrict__ partials,
        int* __restrict__ flags, float* __restrict__ pE, int B) {
    const int tid = threadIdx.x;

    if (blockIdx.x >= NCHUNK) {
        // =================== ROWS PART (one wave per row) ===================
        const int rbid = blockIdx.x - NCHUNK;
        const int row  = (rbid * 256 + tid) >> 6;
        const int lane = tid & 63;
        if (row >= B) return;

        // ---- phase 1: the compulsory x-read — independent of pE ----
        const float4* xr = (const float4*)(x + (size_t)row * DFEAT);
        float prod = 1.f;
#pragma unroll
        for (int it = 0; it < DFEAT / (64 * 4); ++it) {   // 8 coalesced f4
            float4 v = xr[it * 64 + lane];
            prod *= (v.x * v.y) * (v.z * v.w);
        }
#pragma unroll
        for (int off = 32; off > 0; off >>= 1)            // wave-wide product
            prod *= __shfl_xor(prod, off);

        // ---- phase 2: throttled wait for pE (set at ~7us; most waves
        //      arrive after it's set and pass on the first acquire) ----
        while (__hip_atomic_load(&flags[0], __ATOMIC_ACQUIRE,
                                 __HIP_MEMORY_SCOPE_AGENT) != MAGIC)
            __builtin_amdgcn_s_sleep(64);                 // ~4096 cyc nap

        const float pv = pE[lane];                        // lane < 64 == OUTD
        const int   E  = ((const int*)pE)[OUTD];
        out[(size_t)row * OUTD + lane] = ldexpf(pv * prod, E) + bias[lane];
        return;
    }

    // ====================== CHAIN PART (blocks 0..31) =======================
    __shared__ __align__(16) float Cs[2][BATCH * NR2];    // 16 KB ping-pong
    __shared__ float A[2][R][R];                          // 2 KB running prod
    const int i = tid >> 4, j = tid & 15;
    const size_t d0 = (size_t)blockIdx.x * CHUNK;
    const float4* g4 = (const float4*)(cores + d0 * NR2); // 1024 f4 / chunk

    // ---- stage batch 0 (8 matrices = 512 float4, 2/thread) ----
    {
        float4* s4 = (float4*)&Cs[0][0];
        s4[tid]       = g4[tid];
        s4[256 + tid] = g4[256 + tid];
    }
    A[0][i][j] = (i == j) ? 1.f : 0.f;    // identity seed (exact)
    __syncthreads();

    int cur = 0;
    for (int b = 0; b < NBATCH; ++b) {
        const int cb = b & 1;
        float4 pre0, pre1;
        if (b + 1 < NBATCH) {             // prefetch next batch into regs
            pre0 = g4[(b + 1) * 512 + tid];
            pre1 = g4[(b + 1) * 512 + 256 + tid];
        }
        // fold 8 matrices from buffer cb (loads hidden under these)
        for (int t = 0; t < BATCH; ++t) {
            const float* M = &Cs[cb][t * NR2];
            float acc = 0.f;
#pragma unroll
            for (int k = 0; k < R; ++k)
                acc = fmaf(A[cur][i][k], M[k * R + j], acc);
            A[cur ^ 1][i][j] = acc;       // own element only
            cur ^= 1;
            __syncthreads();
        }
        if (b + 1 < NBATCH) {             // buffer cb^1 consumed in batch b-1
            float4* s4 = (float4*)&Cs[cb ^ 1][0];
            s4[tid]       = pre0;
            s4[256 + tid] = pre1;
            __syncthreads();              // writes visible before next fold
        }
    }
    const float v = A[cur][i][j];         // this thread's partial element

    if (blockIdx.x != 0) {
        // ---- producer: publish partial, release flag ----
        partials[blockIdx.x * NR2 + tid] = v;
        __syncthreads();                  // block stores complete at L2
        if (tid == 0)
            __hip_atomic_store(&flags[blockIdx.x], MAGIC,
                               __ATOMIC_RELEASE, __HIP_MEMORY_SCOPE_AGENT);
        return;
    }

    // ---- block 0: publish own partial via global (read back below) ----
    partials[tid] = v;

    // sleepy acquire-spin for producers 1..31 (every thread: acq side effect)
    {
        const int f = 1 + (tid % (NCHUNK - 1));
        while (__hip_atomic_load(&flags[f], __ATOMIC_ACQUIRE,
                                 __HIP_MEMORY_SCOPE_AGENT) != MAGIC)
            __builtin_amdgcn_s_sleep(8);  // be kind to our XCD's L2
    }
    __syncthreads();

    // ---- reduce in two passes of 16 partials, reusing Cs as the transposed
    //      staging area (16 matrices * 1 KB = 16 KB). Wave 0 keeps w,E in
    //      registers across passes. ----
    float* Pt = &Cs[0][0];                // Pt[g][jj][k] = g*256 + jj*16 + k
    float w = 1.f;                        // lane jj holds w[jj] (q-replicated)
    int   E = 0;
    const int jj = tid & 15, q = (tid >> 4) & 3;   // for wave-0 fold

    for (int p = 0; p < 2; ++p) {
        // stage partials p*16 .. p*16+15 transposed: 1024 f4, 4/thread
#pragma unroll
        for (int qq = 0; qq < 4; ++qq) {
            const int idx = qq * 256 + tid;           // f4 idx in pass chunk
            float4 p4 = ((const float4*)(partials + p * 16 * NR2))[idx];
            const int flat = idx * 4;                 // elem in [0,4096)
            const int gl = flat >> 8;                 // local matrix 0..15
            const int e  = flat & 255;
            const int k = e >> 4, j0 = e & 15;
            Pt[gl * 256 + (j0 + 0) * 16 + k] = p4.x;
            Pt[gl * 256 + (j0 + 1) * 16 + k] = p4.y;
            Pt[gl * 256 + (j0 + 2) * 16 + k] = p4.z;
            Pt[gl * 256 + (j0 + 3) * 16 + k] = p4.w;
        }
        __syncthreads();
        if (tid < 64) {                   // wave-0 register fold, no barriers
            for (int gl = 0; gl < 16; ++gl) {
                const float4 pr = *(const float4*)&Pt[gl * 256 + jj * 16 + 4 * q];
                float s;
                s = __shfl(w, 4 * q + 0) * pr.x;      // w[k] lives at lane k
                s = fmaf(__shfl(w, 4 * q + 1), pr.y, s);
                s = fmaf(__shfl(w, 4 * q + 2), pr.z, s);
                s = fmaf(__shfl(w, 4 * q + 3), pr.w, s);
                s += __shfl_xor(s, 16);               // sum 4 q-groups
                s += __shfl_xor(s, 32);               // -> nw[jj], replicated
                w = s;
                if ((gl & 7) == 7) {                  // exact pow2 renorm
                    float m = fabsf(w);
#pragma unroll
                    for (int off = 1; off <= 8; off <<= 1)
                        m = fmaxf(m, __shfl_xor(m, off));
                    if (m > 0.f) {
                        int e = 0;
                        (void)frexpf(m, &e);          // m = f*2^e, f in [.5,1)
                        w = ldexpf(w, -e);            // exact rescale
                        E += e;
                    }
                }
            }
        }
        __syncthreads();                  // fold done before restaging
    }

    if (tid < 64) {
        // p[o] = sum_k w[k] * proj[k][o]
        float pv = 0.f;
#pragma unroll
        for (int k = 0; k < R; ++k)
            pv = fmaf(__shfl(w, k), proj[k * OUTD + tid], pv);
        pE[tid] = pv;
        if (tid == 0) ((int*)pE)[OUTD] = E;
        // one wave: tid0's release-store orders after this wave's pE stores
        if (tid == 0)
            __hip_atomic_store(&flags[0], MAGIC,
                               __ATOMIC_RELEASE, __HIP_MEMORY_SCOPE_AGENT);
    }
}

// ---------------------------------------------------------------------------
extern "C" void kernel_launch(void* const* d_in, const int* in_sizes, int n_in,
                              void* d_out, int out_size, void* d_ws, size_t ws_size,
                              hipStream_t stream) {
    const float* inputs = (const float*)d_in[0];   // (B, 2048) fp32
    const float* cores  = (const float*)d_in[1];   // (2048, 16, 16) fp32
    const float* proj   = (const float*)d_in[2];   // (16, 64) fp32
    const float* bias   = (const float*)d_in[3];   // (64,) fp32
    float* out = (float*)d_out;                    // (B, 64) fp32

    // ws layout (16B aligned): partials | pE (64f + int E, padded) | flags
    float* partials = (float*)d_ws;                // 32*256 floats (32 KiB)
    float* pE    = partials + NCHUNK * NR2;        // 64 floats + int E (+pad)
    int*   flags = (int*)(pE + 68);                // 32 ints; 0xAA poison
                                                   // != MAGIC each replay

    const int B = in_sizes[0] / DFEAT;             // 8192

    const int rowBlocks = (B * 64 + 255) / 256;    // 2048
    mps_fused<<<NCHUNK + rowBlocks, 256, 0, stream>>>(
        cores, proj, inputs, bias, out, partials, flags, pE, B);
}

// Round 9
// 106.101 us; speedup vs baseline: 6.3305x; 6.3305x over previous
//
#include <hip/hip_runtime.h>
#include <math.h>

// out[b] = (1^T · Π_d C_d · P) · Π_d x[b,d] + bias — per-row scalars commute
// out of the batch-independent matrix chain. Two kernels (round-6 structure,
// verified 113.5 us; rounds 7/8 proved intra-kernel producer/consumer fusion
// thrashes the scheduler/L2 on this grid):
//   mps_chain (32 blocks): fold 64-core chunks. NEW: wave-parallel tree fold
//     — each of 4 waves folds 16 matrices privately (4 elems/lane, per-wave
//     LDS ping-pong, wave-synchronous, no barriers), wave 0 combines with 3
//     multiplies. Critical path 64 barriered steps -> 15+3 unbarriered.
//     Fan-in via flags; block 0 reduces 32 partials in wave-0 registers,
//     projects -> pE (verbatim round 6).
//   mps_rows (2048 blocks): compulsory ~64 MB read, one wave/row (verbatim).
// Row products underflow fp32 to 0 exactly as the reference (absmax 0.0,
// verified rounds 1/5/6).

#define DFEAT 2048
#define R 16
#define NR2 256               // R*R
#define OUTD 64
#define CHUNK 64              // cores folded per chain block
#define NCHUNK (DFEAT / CHUNK)    // 32 chain blocks
#define MAGIC 0x7E57C0DE

// (Arow · B)[c0..c0+3]: Arow = 16 LDS floats (4x ds_read_b128), B = 16x16
// row-major LDS matrix. All FMA, no barriers.
__device__ __forceinline__ float4 rowmul(const float* Arow, const float* B,
                                         int c0) {
    float4 acc = {0.f, 0.f, 0.f, 0.f};
    const float4* a4 = (const float4*)Arow;
#pragma unroll
    for (int kk = 0; kk < 4; ++kk) {
        const float4 av = a4[kk];
        const float4 b0 = *(const float4*)&B[(4 * kk + 0) * 16 + c0];
        const float4 b1 = *(const float4*)&B[(4 * kk + 1) * 16 + c0];
        const float4 b2 = *(const float4*)&B[(4 * kk + 2) * 16 + c0];
        const float4 b3 = *(const float4*)&B[(4 * kk + 3) * 16 + c0];
        acc.x = fmaf(av.x, b0.x, fmaf(av.y, b1.x, fmaf(av.z, b2.x, fmaf(av.w, b3.x, acc.x))));
        acc.y = fmaf(av.x, b0.y, fmaf(av.y, b1.y, fmaf(av.z, b2.y, fmaf(av.w, b3.y, acc.y))));
        acc.z = fmaf(av.x, b0.z, fmaf(av.y, b1.z, fmaf(av.z, b2.z, fmaf(av.w, b3.z, acc.z))));
        acc.w = fmaf(av.x, b0.w, fmaf(av.y, b1.w, fmaf(av.z, b2.w, fmaf(av.w, b3.w, acc.w))));
    }
    return acc;
}

__global__ __launch_bounds__(256) void mps_chain(const float* __restrict__ cores,
                                                 const float* __restrict__ proj,
                                                 float* __restrict__ partials,
                                                 int* __restrict__ flags,
                                                 float* __restrict__ pE) {
    __shared__ __align__(16) float Cs[CHUNK * NR2];     // 64 KB staged cores
    __shared__ __align__(16) float Aw[4][2][NR2];       // 8 KB per-wave pp
    __shared__ __align__(16) float F[2][NR2];           // 2 KB combine pp
    __shared__ __align__(16) float Pt[NCHUNK * NR2];    // 32 KB transposed
    const int tid  = threadIdx.x;
    const int wave = tid >> 6, lane = tid & 63;
    const int ri = lane >> 2;             // row 0..15 (this lane's A/F row)
    const int c0 = (lane & 3) << 2;       // col base 0,4,8,12
    const size_t d0 = (size_t)blockIdx.x * CHUNK;

    // ---- stage all 64 cores: 4096 float4, 16/thread, coalesced ----
    const float4* g4 = (const float4*)(cores + d0 * NR2);
    float4* s4 = (float4*)&Cs[0];
#pragma unroll
    for (int q = 0; q < 16; ++q)
        s4[q * 256 + tid] = g4[q * 256 + tid];
    __syncthreads();

    // ---- per-wave fold of 16 matrices, wave-synchronous (no barriers) ----
    // (within-wave ds_write -> ds_read ordering via lgkmcnt; lockstep wave64)
    *(float4*)&Aw[wave][0][ri * 16 + c0] =
        *(const float4*)&Cs[(16 * wave) * NR2 + ri * 16 + c0];
    int cur = 0;
    for (int t = 1; t < 16; ++t) {        // 15 multiplies -> result in buf 1
        float4 r = rowmul(&Aw[wave][cur][ri * 16],
                          &Cs[(16 * wave + t) * NR2], c0);
        *(float4*)&Aw[wave][cur ^ 1][ri * 16 + c0] = r;
        cur ^= 1;
    }
    __syncthreads();                      // all 4 wave-products ready

    // ---- wave 0 combines: F = Aw0 x Aw1 x Aw2 x Aw3 (3 multiplies) ----
    if (wave == 0) {
        *(float4*)&F[0][ri * 16 + c0] =
            *(const float4*)&Aw[0][1][ri * 16 + c0];
        int cc = 0;
        for (int w = 1; w < 4; ++w) {     // 3 multiplies -> result in F[1]
            float4 r = rowmul(&F[cc][ri * 16], &Aw[w][1][0], c0);
            *(float4*)&F[cc ^ 1][ri * 16 + c0] = r;
            cc ^= 1;
        }
    }
    __syncthreads();
    const int i = tid >> 4, j = tid & 15;
    const float v = F[1][tid];            // element (i,j) of chunk product

    if (blockIdx.x != 0) {
        // ---- producer: publish partial, release flag (verbatim round 6) ----
        partials[blockIdx.x * NR2 + tid] = v;
        __syncthreads();                  // block stores complete at L2
        if (tid == 0)
            __hip_atomic_store(&flags[blockIdx.x], MAGIC,
                               __ATOMIC_RELEASE, __HIP_MEMORY_SCOPE_AGENT);
        return;
    }

    // ---- block 0: own partial straight into LDS (transposed) ----
    Pt[0 * 256 + j * 16 + i] = v;

    // acquire-spin for producers 1..31 (every thread: cache-inv side effect)
    {
        const int f = 1 + (tid % (NCHUNK - 1));
        while (__hip_atomic_load(&flags[f], __ATOMIC_ACQUIRE,
                                 __HIP_MEMORY_SCOPE_AGENT) != MAGIC) { }
    }
    __syncthreads();

    // ---- stage partials 1..31 into LDS transposed: 1984 float4 coalesced ---
#pragma unroll
    for (int q = 0; q < 8; ++q) {
        const int idx = q * 256 + tid;                // float4 index
        if (idx < (NCHUNK - 1) * 64) {
            float4 p4 = ((const float4*)(partials + NR2))[idx];
            const int flat = idx * 4;
            const int gg = (flat >> 8) + 1;           // which partial (1..31)
            const int e = flat & 255;
            const int k = e >> 4, j0 = e & 15;        // row k, cols j0..j0+3
            Pt[gg * 256 + (j0 + 0) * 16 + k] = p4.x;
            Pt[gg * 256 + (j0 + 1) * 16 + k] = p4.y;
            Pt[gg * 256 + (j0 + 2) * 16 + k] = p4.z;
            Pt[gg * 256 + (j0 + 3) * 16 + k] = p4.w;
        }
    }
    __syncthreads();

    // ---- wave-0 register fold: w <- w @ P_g, g = 0..31 (verbatim rd 6) ----
    if (tid < 64) {
        const int jj = tid & 15, q = tid >> 4;        // lane = jj + 16*q
        float w = 1.f;                                // w[jj], replicated in q
        int E = 0;
        for (int gg = 0; gg < NCHUNK; ++gg) {
            const float4 pr = *(const float4*)&Pt[gg * 256 + jj * 16 + 4 * q];
            float s;
            s = __shfl(w, 4 * q + 0) * pr.x;          // w[k] lives at lane k
            s = fmaf(__shfl(w, 4 * q + 1), pr.y, s);
            s = fmaf(__shfl(w, 4 * q + 2), pr.z, s);
            s = fmaf(__shfl(w, 4 * q + 3), pr.w, s);
            s += __shfl_xor(s, 16);                   // sum the 4 q-groups
            s += __shfl_xor(s, 32);                   // -> nw[jj], replicated
            w = s;
            if ((gg & 7) == 7) {                      // exact pow2 renorm
                float m = fabsf(w);
#pragma unroll
                for (int off = 1; off <= 8; off <<= 1)
                    m = fmaxf(m, __shfl_xor(m, off));
                if (m > 0.f) {
                    int e = 0;
                    (void)frexpf(m, &e);              // m = f*2^e, f in [.5,1)
                    w = ldexpf(w, -e);                // exact rescale
                    E += e;
                }
            }
        }
        // p[o] = sum_k w[k] * proj[k][o]
        float p = 0.f;
#pragma unroll
        for (int k = 0; k < R; ++k)
            p = fmaf(__shfl(w, k), proj[k * OUTD + tid], p);
        pE[tid] = p;
        if (tid == 0) ((int*)pE)[OUTD] = E;
    }
}

// ---------------------------------------------------------------------------
// One wave per batch row (verbatim rounds 5/6; at the memory roofline).
// ---------------------------------------------------------------------------
__global__ __launch_bounds__(256) void mps_rows(const float* __restrict__ x,
                                                const float* __restrict__ pE,
                                                const float* __restrict__ bias,
                                                float* __restrict__ out,
                                                int B) {
    const int gtid = blockIdx.x * 256 + threadIdx.x;
    const int row  = gtid >> 6;           // wave id == row
    const int lane = threadIdx.x & 63;
    if (row >= B) return;

    const float4* xr = (const float4*)(x + (size_t)row * DFEAT);
    float prod = 1.f;
#pragma unroll
    for (int it = 0; it < DFEAT / (64 * 4); ++it) {   // 8 iters, 1 KiB/instr
        float4 v = xr[it * 64 + lane];
        prod *= (v.x * v.y) * (v.z * v.w);
    }
#pragma unroll
    for (int off = 32; off > 0; off >>= 1)            // wave-wide product
        prod *= __shfl_xor(prod, off);

    const float pv = pE[lane];                        // lane < 64 == OUTD
    const int   E  = ((const int*)pE)[OUTD];
    out[(size_t)row * OUTD + lane] = ldexpf(pv * prod, E) + bias[lane];
}

// ---------------------------------------------------------------------------
extern "C" void kernel_launch(void* const* d_in, const int* in_sizes, int n_in,
                              void* d_out, int out_size, void* d_ws, size_t ws_size,
                              hipStream_t stream) {
    const float* inputs = (const float*)d_in[0];   // (B, 2048) fp32
    const float* cores  = (const float*)d_in[1];   // (2048, 16, 16) fp32
    const float* proj   = (const float*)d_in[2];   // (16, 64) fp32
    const float* bias   = (const float*)d_in[3];   // (64,) fp32
    float* out = (float*)d_out;                    // (B, 64) fp32

    // ws layout (16B aligned): partials | pE (64f + int E, padded) | flags
    float* partials = (float*)d_ws;                // 32*256 floats (32 KiB)
    float* pE    = partials + NCHUNK * NR2;        // 64 floats + int E (+pad)
    int*   flags = (int*)(pE + 68);                // 32 ints; 0xAA poison
                                                   // != MAGIC each replay

    const int B = in_sizes[0] / DFEAT;             // 8192

    mps_chain<<<NCHUNK, 256, 0, stream>>>(cores, proj, partials, flags, pE);
    mps_rows<<<(B * 64 + 255) / 256, 256, 0, stream>>>(inputs, pE, bias, out, B);
}